// Round 5
// baseline (7429.854 us; speedup 1.0000x reference)
//
#include <hip/hip_runtime.h>

// NeuralODE: B=1024, D=64, F=8, H=256, 196 substeps x 6 dopri5 stages.
// R5: wave specialization. R2-R4 showed the allocator caps arch VGPRs at 128
// (unified-file split) and parks overflow weights in AGPRs -> v_accvgpr_read
// per use. Fix: make the live set fit 128 BY CONSTRUCTION.
//   512-thread blocks, 2 batch rows/block, 512 blocks -> 2 blocks/CU
//   (16 waves/CU, 4 waves/EU, VGPR budget 512/4 = 128).
//   waves 0-3 (ph1): thread owns W1[:,tid] (72 regs); computes h[r][tid], r=0,1
//   waves 4-7 (ph2): thread (g=w-4, d=l) owns W2[g*64..+63][d] (64 regs);
//                    computes k partials both rows; waves 4,5 carry ODE state.
// Max live ~107 regs -> no AGPR traffic. Each SIMD: 2 ph1 + 2 ph2 waves from
// 2 independent blocks -> phase serialization hidden across blocks.
// All hot LDS reads are wave-uniform broadcasts; red stride 5 (2-way, free).

__device__ __forceinline__ float fast_tanh(float x) {
    float e = __expf(2.0f * x);
    return 1.0f - 2.0f / (e + 1.0f);   // saturates correctly, ~1e-6 abs err
}

__global__ __attribute__((amdgpu_waves_per_eu(4, 4))) __launch_bounds__(512)
void node_kernel(const float* __restrict__ x0,
                 const float* __restrict__ t_eval,
                 const float* __restrict__ t_u,
                 const float* __restrict__ u_batch,
                 const float* __restrict__ W1,
                 const float* __restrict__ b1,
                 const float* __restrict__ W2,
                 const float* __restrict__ b2,
                 float* __restrict__ out)
{
    __shared__ __align__(16) float zsh[2][72];     // [row][D+F]
    __shared__ __align__(16) float hsh[2][256];    // [row][hidden]
    __shared__ __align__(16) float red[2][64][5];  // [row][d][chunk g], stride 5
    __shared__ __align__(16) float ush[6][2][8];   // interp u per stage/row

    const int tid = threadIdx.x;
    const int w   = tid >> 6;            // wave 0-7
    const int l   = tid & 63;
    const bool is_p1 = (w < 4);          // wave-uniform
    const int blk = blockIdx.x;

    // --- weights: disjoint per duty, each fits well under 128 VGPRs ---
    float w1r[72];                       // ph1: W1[:, c], c = tid (0..255)
    float w2r[64];                       // ph2: W2[g*64+j][d]
    const int c = tid & 255;
    const int g = w & 3;                 // ph2 chunk 0..3
    if (is_p1) {
#pragma unroll
        for (int i = 0; i < 72; ++i) w1r[i] = W1[i * 256 + c];
#pragma unroll
        for (int i = 0; i < 72; ++i) asm("" : "+v"(w1r[i]));
    } else {
#pragma unroll
        for (int j = 0; j < 64; ++j) w2r[j] = W2[(g * 64 + j) * 64 + l];
#pragma unroll
        for (int j = 0; j < 64; ++j) asm("" : "+v"(w2r[j]));
    }
    const float b1c = b1[c];
    const float b2d = b2[l];

    // --- ODE state: wave 4 -> row 0, wave 5 -> row 1 (lane l = dim l) ---
    const bool is_st = (w == 4) || (w == 5);
    const int  r     = w - 4;            // valid when is_st
    float x = 0.f;
    if (is_st) {
        x = x0[(blk * 2 + r) * 64 + l];
        out[(blk * 2 + r) * 3200 + l] = x;      // t_eval[0]
    }
    float k1 = 0.f, k2 = 0.f, k3 = 0.f, k4 = 0.f, k5 = 0.f, k6 = 0.f;

#pragma unroll 1
    for (int step = 0; step < 196; ++step) {
        const int n = step >> 2;
        const int m = step & 3;
        const float te0 = t_eval[n];
        const float dtc = t_eval[n + 1] - te0;
        const float t   = te0 + dtc * (0.25f * (float)m);
        const float dt  = dtc * 0.25f;

        // --- prefetch+interp u for all 6 stages (ph1-side threads 0..95) ---
        if (tid < 96) {
            const int s  = tid >> 4;
            const int rr = (tid >> 3) & 1;
            const int f  = tid & 7;
            float tsv;
            switch (s) {
                case 0: tsv = t; break;
                case 1: tsv = t + dt * (1.0f/5.0f); break;
                case 2: tsv = t + dt * (3.0f/10.0f); break;
                case 3: tsv = t + dt * (4.0f/5.0f); break;
                case 4: tsv = t + dt * (8.0f/9.0f); break;
                default: tsv = t + dt; break;
            }
            int idx = (int)(tsv * 127.0f);       // == searchsorted-1 (gap >= 4e-5)
            idx = idx < 0 ? 0 : (idx > 126 ? 126 : idx);
            const float ta = t_u[idx];
            const float tb = t_u[idx + 1];
            const float wt = (tsv - ta) / (tb - ta);
            const int base = (blk * 2 + rr) * (128 * 8) + idx * 8 + f;
            const float u0v = u_batch[base];
            const float u1v = u_batch[base + 8];
            ush[s][rr][f] = fmaf(wt, u1v - u0v, u0v);
        }
        __syncthreads();

#pragma unroll 1
        for (int s = 0; s < 6; ++s) {
            // --- staging: state waves publish z = [x_s, u_s] ---
            if (is_st) {
                float xs;
                switch (s) {
                    case 0: xs = x; break;
                    case 1: xs = fmaf(dt, k1 * (1.0f/5.0f), x); break;
                    case 2: xs = fmaf(dt, fmaf(3.0f/40.0f, k1, (9.0f/40.0f)*k2), x); break;
                    case 3: xs = fmaf(dt, (44.0f/45.0f)*k1 + (-56.0f/15.0f)*k2 + (32.0f/9.0f)*k3, x); break;
                    case 4: xs = fmaf(dt, (19372.0f/6561.0f)*k1 + (-25360.0f/2187.0f)*k2
                                         + (64448.0f/6561.0f)*k3 + (-212.0f/729.0f)*k4, x); break;
                    default: xs = fmaf(dt, (9017.0f/3168.0f)*k1 + (-355.0f/33.0f)*k2
                                          + (46732.0f/5247.0f)*k3 + (49.0f/176.0f)*k4
                                          + (-5103.0f/18656.0f)*k5, x); break;
                }
                zsh[r][l] = xs;
                if (l < 8) zsh[r][64 + l] = ush[s][r][l];
            }
            __syncthreads();

            // --- phase 1 (waves 0-3): h[row][c] = tanh(z[row].W1[:,c]+b1) ---
            if (is_p1) {
                float a0 = b1c, a1 = b1c;
#pragma unroll
                for (int i = 0; i < 72; i += 4) {
                    const float4 z0 = *(const float4*)&zsh[0][i];
                    const float4 z1 = *(const float4*)&zsh[1][i];
                    a0 = fmaf(z0.x, w1r[i],   a0);  a1 = fmaf(z1.x, w1r[i],   a1);
                    a0 = fmaf(z0.y, w1r[i+1], a0);  a1 = fmaf(z1.y, w1r[i+1], a1);
                    a0 = fmaf(z0.z, w1r[i+2], a0);  a1 = fmaf(z1.z, w1r[i+2], a1);
                    a0 = fmaf(z0.w, w1r[i+3], a0);  a1 = fmaf(z1.w, w1r[i+3], a1);
                }
                hsh[0][c] = fast_tanh(a0);
                hsh[1][c] = fast_tanh(a1);
            }
            __syncthreads();

            // --- phase 2 (waves 4-7): partials over 64-j chunk, both rows ---
            if (!is_p1) {
                float p0 = 0.f, p1 = 0.f;
                const int jb = g * 64;
#pragma unroll
                for (int j = 0; j < 64; j += 4) {
                    const float4 h0 = *(const float4*)&hsh[0][jb + j];
                    const float4 h1 = *(const float4*)&hsh[1][jb + j];
                    p0 = fmaf(h0.x, w2r[j],   p0);  p1 = fmaf(h1.x, w2r[j],   p1);
                    p0 = fmaf(h0.y, w2r[j+1], p0);  p1 = fmaf(h1.y, w2r[j+1], p1);
                    p0 = fmaf(h0.z, w2r[j+2], p0);  p1 = fmaf(h1.z, w2r[j+2], p1);
                    p0 = fmaf(h0.w, w2r[j+3], p0);  p1 = fmaf(h1.w, w2r[j+3], p1);
                }
                red[0][l][g] = p0;
                red[1][l][g] = p1;
            }
            __syncthreads();

            // --- reduce 4 chunks -> k (state waves) ---
            if (is_st) {
                const float* rp = red[r][l];
                const float kv = b2d + ((rp[0] + rp[1]) + (rp[2] + rp[3]));
                switch (s) {
                    case 0: k1 = kv; break;
                    case 1: k2 = kv; break;
                    case 2: k3 = kv; break;
                    case 3: k4 = kv; break;
                    case 4: k5 = kv; break;
                    default: k6 = kv; break;
                }
            }
        }

        // --- dopri5 update ---
        if (is_st) {
            x = fmaf(dt, (35.0f/384.0f)*k1 + (500.0f/1113.0f)*k3 + (125.0f/192.0f)*k4
                        + (-2187.0f/6784.0f)*k5 + (11.0f/84.0f)*k6, x);
            if (m == 3) out[(blk * 2 + r) * 3200 + (n + 1) * 64 + l] = x;
        }
    }
}

extern "C" void kernel_launch(void* const* d_in, const int* in_sizes, int n_in,
                              void* d_out, int out_size, void* d_ws, size_t ws_size,
                              hipStream_t stream) {
    const float* x0      = (const float*)d_in[0];
    const float* t_eval  = (const float*)d_in[1];
    const float* t_u     = (const float*)d_in[2];
    const float* u_batch = (const float*)d_in[3];
    const float* W1      = (const float*)d_in[4];
    const float* b1      = (const float*)d_in[5];
    const float* W2      = (const float*)d_in[6];
    const float* b2      = (const float*)d_in[7];
    float* out = (float*)d_out;

    node_kernel<<<dim3(512), dim3(512), 0, stream>>>(
        x0, t_eval, t_u, u_batch, W1, b1, W2, b2, out);
}

// Round 6
// 1913.551 us; speedup vs baseline: 3.8828x; 3.8828x over previous
//
#include <hip/hip_runtime.h>

// NeuralODE: B=1024, D=64, F=8, H=256, 196 substeps x 6 dopri5 stages.
// R6: wave specialization with ONE shared register array.
// R5 failed because w1r[72]+w2r[64] were both statically live in every
// thread (136 > the 128-reg budget at waves_per_eu(4,4)) -> scratch spill
// (WRITE_SIZE 12.8 MB -> 952 MB, VALUBusy 15%). Register allocation is
// static per thread, so the two duties must SHARE storage: one wreg[72],
// ph1 waves fill it with W1[:,c], ph2 waves with their W2 chunk (64 elems).
// Live set ~107 < 128 by construction -> no AGPR, no scratch.
//   512 blocks x 512 threads, 2 batch rows/block, 2 blocks/CU
//   (16 waves/CU, 4 waves/EU; each SIMD hosts 1 ph1 + 1 ph2 wave per block).
//   waves 0-3 (ph1): thread owns W1[:,c], c=tid&255; computes h[0..1][c]
//   waves 4-7 (ph2): thread (g=w&3, d=l) owns W2[g*64..+63][d]; both rows;
//                    waves 4,5 carry ODE state rows 0,1 (lane l = dim l).
// All hot LDS reads are wave-uniform broadcasts; red stride 5 (2-way, free).

__device__ __forceinline__ float fast_tanh(float x) {
    float e = __expf(2.0f * x);
    return 1.0f - 2.0f / (e + 1.0f);   // saturates correctly, ~1e-6 abs err
}

__global__ __attribute__((amdgpu_waves_per_eu(4, 4))) __launch_bounds__(512)
void node_kernel(const float* __restrict__ x0,
                 const float* __restrict__ t_eval,
                 const float* __restrict__ t_u,
                 const float* __restrict__ u_batch,
                 const float* __restrict__ W1,
                 const float* __restrict__ b1,
                 const float* __restrict__ W2,
                 const float* __restrict__ b2,
                 float* __restrict__ out)
{
    __shared__ __align__(16) float zsh[2][72];     // [row][D+F]
    __shared__ __align__(16) float hsh[2][256];    // [row][hidden]
    __shared__ __align__(16) float red[2][64][5];  // [row][d][chunk g], stride 5
    __shared__ __align__(16) float ush[6][2][8];   // interp u per stage/row

    const int tid = threadIdx.x;
    const int w   = tid >> 6;            // wave 0-7
    const int l   = tid & 63;
    const bool is_p1 = (w < 4);          // wave-uniform
    const int blk = blockIdx.x;
    const int c   = tid & 255;           // ph1 column
    const int g   = w & 3;               // ph2 j-chunk
    const bool is_st = (w == 4) || (w == 5);
    const int r   = w & 1;               // state row (valid when is_st)

    // --- ONE register array, duty-dependent contents (shared storage) ---
    float wreg[72];
    if (is_p1) {
#pragma unroll
        for (int i = 0; i < 72; ++i) wreg[i] = W1[i * 256 + c];
#pragma unroll
        for (int i = 0; i < 72; ++i) asm("" : "+v"(wreg[i]));
    } else {
#pragma unroll
        for (int j = 0; j < 64; ++j) wreg[j] = W2[(g * 64 + j) * 64 + l];
#pragma unroll
        for (int j = 0; j < 64; ++j) asm("" : "+v"(wreg[j]));
    }
    const float b1c = b1[c];
    const float b2d = b2[l];

    // --- ODE state: wave 4 -> row 0, wave 5 -> row 1 ---
    float x = 0.f;
    if (is_st) {
        x = x0[(blk * 2 + r) * 64 + l];
        out[(blk * 2 + r) * 3200 + l] = x;      // t_eval[0]
    }
    float k1 = 0.f, k2 = 0.f, k3 = 0.f, k4 = 0.f, k5 = 0.f, k6 = 0.f;

#pragma unroll 1
    for (int step = 0; step < 196; ++step) {
        const int n = step >> 2;
        const int m = step & 3;
        const float te0 = t_eval[n];
        const float dtc = t_eval[n + 1] - te0;
        const float t   = te0 + dtc * (0.25f * (float)m);
        const float dt  = dtc * 0.25f;

        // --- prefetch+interp u for all 6 stages (threads 0..95, ph1 side) ---
        if (tid < 96) {
            const int s  = tid >> 4;
            const int rr = (tid >> 3) & 1;
            const int f  = tid & 7;
            float tsv;
            switch (s) {
                case 0: tsv = t; break;
                case 1: tsv = t + dt * (1.0f/5.0f); break;
                case 2: tsv = t + dt * (3.0f/10.0f); break;
                case 3: tsv = t + dt * (4.0f/5.0f); break;
                case 4: tsv = t + dt * (8.0f/9.0f); break;
                default: tsv = t + dt; break;
            }
            int idx = (int)(tsv * 127.0f);       // == searchsorted-1 (gap >= 4e-5)
            idx = idx < 0 ? 0 : (idx > 126 ? 126 : idx);
            const float ta = t_u[idx];
            const float tb = t_u[idx + 1];
            const float wt = (tsv - ta) / (tb - ta);
            const int base = (blk * 2 + rr) * (128 * 8) + idx * 8 + f;
            const float u0v = u_batch[base];
            const float u1v = u_batch[base + 8];
            ush[s][rr][f] = fmaf(wt, u1v - u0v, u0v);
        }
        __syncthreads();

#pragma unroll 1
        for (int s = 0; s < 6; ++s) {
            // --- staging: state waves publish z = [x_s, u_s] ---
            if (is_st) {
                float xs;
                switch (s) {
                    case 0: xs = x; break;
                    case 1: xs = fmaf(dt, k1 * (1.0f/5.0f), x); break;
                    case 2: xs = fmaf(dt, fmaf(3.0f/40.0f, k1, (9.0f/40.0f)*k2), x); break;
                    case 3: xs = fmaf(dt, (44.0f/45.0f)*k1 + (-56.0f/15.0f)*k2 + (32.0f/9.0f)*k3, x); break;
                    case 4: xs = fmaf(dt, (19372.0f/6561.0f)*k1 + (-25360.0f/2187.0f)*k2
                                         + (64448.0f/6561.0f)*k3 + (-212.0f/729.0f)*k4, x); break;
                    default: xs = fmaf(dt, (9017.0f/3168.0f)*k1 + (-355.0f/33.0f)*k2
                                          + (46732.0f/5247.0f)*k3 + (49.0f/176.0f)*k4
                                          + (-5103.0f/18656.0f)*k5, x); break;
                }
                zsh[r][l] = xs;
                if (l < 8) zsh[r][64 + l] = ush[s][r][l];
            }
            __syncthreads();

            // --- phase 1 (waves 0-3): h[row][c] = tanh(z[row].W1[:,c]+b1) ---
            if (is_p1) {
                float a0 = b1c, a1 = b1c;
#pragma unroll
                for (int i = 0; i < 72; i += 4) {
                    const float4 z0 = *(const float4*)&zsh[0][i];
                    const float4 z1 = *(const float4*)&zsh[1][i];
                    a0 = fmaf(z0.x, wreg[i],   a0);  a1 = fmaf(z1.x, wreg[i],   a1);
                    a0 = fmaf(z0.y, wreg[i+1], a0);  a1 = fmaf(z1.y, wreg[i+1], a1);
                    a0 = fmaf(z0.z, wreg[i+2], a0);  a1 = fmaf(z1.z, wreg[i+2], a1);
                    a0 = fmaf(z0.w, wreg[i+3], a0);  a1 = fmaf(z1.w, wreg[i+3], a1);
                }
                hsh[0][c] = fast_tanh(a0);
                hsh[1][c] = fast_tanh(a1);
            }
            __syncthreads();

            // --- phase 2 (waves 4-7): partials over 64-j chunk, both rows ---
            if (!is_p1) {
                float p0 = 0.f, p1 = 0.f;
                const int jb = g * 64;
#pragma unroll
                for (int j = 0; j < 64; j += 4) {
                    const float4 h0 = *(const float4*)&hsh[0][jb + j];
                    const float4 h1 = *(const float4*)&hsh[1][jb + j];
                    p0 = fmaf(h0.x, wreg[j],   p0);  p1 = fmaf(h1.x, wreg[j],   p1);
                    p0 = fmaf(h0.y, wreg[j+1], p0);  p1 = fmaf(h1.y, wreg[j+1], p1);
                    p0 = fmaf(h0.z, wreg[j+2], p0);  p1 = fmaf(h1.z, wreg[j+2], p1);
                    p0 = fmaf(h0.w, wreg[j+3], p0);  p1 = fmaf(h1.w, wreg[j+3], p1);
                }
                red[0][l][g] = p0;
                red[1][l][g] = p1;
            }
            __syncthreads();

            // --- reduce 4 chunks -> k (state waves) ---
            if (is_st) {
                const float* rp = red[r][l];
                const float kv = b2d + ((rp[0] + rp[1]) + (rp[2] + rp[3]));
                switch (s) {
                    case 0: k1 = kv; break;
                    case 1: k2 = kv; break;
                    case 2: k3 = kv; break;
                    case 3: k4 = kv; break;
                    case 4: k5 = kv; break;
                    default: k6 = kv; break;
                }
            }
        }

        // --- dopri5 update ---
        if (is_st) {
            x = fmaf(dt, (35.0f/384.0f)*k1 + (500.0f/1113.0f)*k3 + (125.0f/192.0f)*k4
                        + (-2187.0f/6784.0f)*k5 + (11.0f/84.0f)*k6, x);
            if (m == 3) out[(blk * 2 + r) * 3200 + (n + 1) * 64 + l] = x;
        }
    }
}

extern "C" void kernel_launch(void* const* d_in, const int* in_sizes, int n_in,
                              void* d_out, int out_size, void* d_ws, size_t ws_size,
                              hipStream_t stream) {
    const float* x0      = (const float*)d_in[0];
    const float* t_eval  = (const float*)d_in[1];
    const float* t_u     = (const float*)d_in[2];
    const float* u_batch = (const float*)d_in[3];
    const float* W1      = (const float*)d_in[4];
    const float* b1      = (const float*)d_in[5];
    const float* W2      = (const float*)d_in[6];
    const float* b2      = (const float*)d_in[7];
    float* out = (float*)d_out;

    node_kernel<<<dim3(512), dim3(512), 0, stream>>>(
        x0, t_eval, t_u, u_batch, W1, b1, W2, b2, out);
}